// Round 1
// baseline (91.769 us; speedup 1.0000x reference)
//
#include <hip/hip_runtime.h>

// FeatureScaling: per-feature piecewise-linear interpolation.
// inputs [B=8, N=2e6, F=3] f32 (f innermost), map_from/map_to [F=3, K=17] f32.
// out[b,n,f] = lerp over segment idx = clip(searchsorted(map_from[f], x, 'right')-1, 0, K-2)
//
// Memory-bound: 192 MB in + 192 MB out. Strategy: float4 grid-stride,
// breakpoint tables staged in LDS (102 floats), branchless bin search.

#define KBP 17
#define NF 3

__global__ __launch_bounds__(256) void FeatureScaling_42752104464652_kernel(
    const float* __restrict__ in,
    const float* __restrict__ map_from,
    const float* __restrict__ map_to,
    float* __restrict__ out,
    long long n4 /* number of float4 elements */, long long n_total)
{
    __shared__ float s_from[NF * KBP];
    __shared__ float s_to[NF * KBP];
    const int t = threadIdx.x;
    if (t < NF * KBP) {
        s_from[t] = map_from[t];
        s_to[t]   = map_to[t];
    }
    __syncthreads();

    const long long stride = (long long)gridDim.x * blockDim.x;
    long long i = (long long)blockIdx.x * blockDim.x + t;

    for (; i < n4; i += stride) {
        float4 x4 = reinterpret_cast<const float4*>(in)[i];
        float xv[4] = {x4.x, x4.y, x4.z, x4.w};
        float rv[4];

        // f for element (i*4 + j): since 4 % 3 == 1, (i*4) % 3 == i % 3.
        int m = (int)(i % 3);

        #pragma unroll
        for (int j = 0; j < 4; ++j) {
            int f = m + j;
            f -= (f >= 3) ? 3 : 0;
            f -= (f >= 3) ? 3 : 0;  // j can be up to 3 -> m+j up to 5
            const float* xs = &s_from[f * KBP];
            const float* ys = &s_to[f * KBP];
            const float x = xv[j];

            // idx = clip(count(xs[k] <= x) - 1, 0, K-2) == sum_{k=1..K-2}(x >= xs[k])
            int idx = 0;
            #pragma unroll
            for (int k = 1; k <= KBP - 2; ++k) {
                idx += (x >= xs[k]) ? 1 : 0;
            }

            const float x1 = xs[idx], x2 = xs[idx + 1];
            const float y1 = ys[idx], y2 = ys[idx + 1];
            rv[j] = y1 + (x - x1) * ((y2 - y1) / (x2 - x1));
        }

        reinterpret_cast<float4*>(out)[i] = make_float4(rv[0], rv[1], rv[2], rv[3]);
    }

    // Tail (n_total not multiple of 4) — not hit for 48M elements, kept for safety.
    long long tail_start = n4 * 4;
    long long ti = tail_start + (long long)blockIdx.x * blockDim.x + t;
    for (; ti < n_total; ti += stride) {
        const float x = in[ti];
        int f = (int)(ti % 3);
        const float* xs = &s_from[f * KBP];
        const float* ys = &s_to[f * KBP];
        int idx = 0;
        #pragma unroll
        for (int k = 1; k <= KBP - 2; ++k) idx += (x >= xs[k]) ? 1 : 0;
        const float x1 = xs[idx], x2 = xs[idx + 1];
        const float y1 = ys[idx], y2 = ys[idx + 1];
        out[ti] = y1 + (x - x1) * ((y2 - y1) / (x2 - x1));
    }
}

extern "C" void kernel_launch(void* const* d_in, const int* in_sizes, int n_in,
                              void* d_out, int out_size, void* d_ws, size_t ws_size,
                              hipStream_t stream) {
    const float* in       = (const float*)d_in[0];
    const float* map_from = (const float*)d_in[1];
    const float* map_to   = (const float*)d_in[2];
    float* out            = (float*)d_out;

    const long long n_total = (long long)in_sizes[0];  // 48,000,000
    const long long n4 = n_total / 4;

    const int block = 256;
    long long want = (n4 + block - 1) / block;
    int grid = (int)((want < 2048) ? (want > 0 ? want : 1) : 2048);

    FeatureScaling_42752104464652_kernel<<<grid, block, 0, stream>>>(
        in, map_from, map_to, out, n4, n_total);
}